// Round 2
// baseline (64685.333 us; speedup 1.0000x reference)
//
#include <hip/hip_runtime.h>
#include <math.h>

// KNRM-style ranker, fp32 end-to-end (kernel-0 sigma=1e-4 makes sim
// precision-critical at ~1e-5: bf16/MFMA would flip exp-window hits).
// R2: deswizzled/despilled GEMM (ext_vector acc, launch_bounds(256,2)),
// double-buffered LDS with reg-staged prefetch, 256-thread attention.

#define DMODEL 256
typedef float f32x4 __attribute__((ext_vector_type(4)));

// ---------------- embed + positional encoding ----------------
__global__ __launch_bounds__(256) void k_embed(const int* __restrict__ ids,
    const float* __restrict__ emb, float* __restrict__ out_x, int S) {
  int tok = blockIdx.x;
  int d = threadIdx.x;
  int id = ids[tok];
  float m = id > 0 ? 1.f : 0.f;
  float e = emb[(size_t)id * DMODEL + d] * m;
  int s = tok % S;
  int i2 = d & ~1;
  float freq = expf((float)i2 * (-9.210340371976184f / 256.f));
  float ang = (float)s * freq;
  float pe = (d & 1) ? cosf(ang) : sinf(ang);
  out_x[(size_t)tok * DMODEL + d] = 2.f * e + pe;
}

// ---------------- fp32 GEMM: out[M,N] = X[M,K] @ W[N,K]^T + bias (opt ReLU) ----
// 128x128x16 tile, 256 threads, 8x8 micro (4+4 split), double-buffered LDS,
// register-staged prefetch: loads for tile t+1 issued before compute of t.
template<bool RELU>
__global__ __launch_bounds__(256, 2) void k_gemm(const float* __restrict__ X,
    const float* __restrict__ W, const float* __restrict__ bias,
    float* __restrict__ out, int M, int N, int K) {
  __shared__ float As[2][16][128];
  __shared__ float Bs[2][16][128];
  const int tid = threadIdx.x;
  const int n0 = blockIdx.x * 128;
  const int m0 = blockIdx.y * 128;
  const int tx = tid & 15, ty = tid >> 4;
  const int lr = tid >> 1;
  const int lk = (tid & 1) << 3;
  const float* Xp = X + (size_t)(m0 + lr) * K + lk;
  const float* Wp = W + (size_t)(n0 + lr) * K + lk;

  f32x4 acc[8][2];
#pragma unroll
  for (int i = 0; i < 8; ++i) { acc[i][0] = 0.f; acc[i][1] = 0.f; }

  // prologue: stage tile 0 into buf 0
  f32x4 ra0 = *(const f32x4*)(Xp);
  f32x4 ra1 = *(const f32x4*)(Xp + 4);
  f32x4 rb0 = *(const f32x4*)(Wp);
  f32x4 rb1 = *(const f32x4*)(Wp + 4);
#pragma unroll
  for (int j = 0; j < 4; ++j) {
    As[0][lk + j][lr] = ra0[j];  As[0][lk + 4 + j][lr] = ra1[j];
    Bs[0][lk + j][lr] = rb0[j];  Bs[0][lk + 4 + j][lr] = rb1[j];
  }
  __syncthreads();

  const int nt = K >> 4;
  int buf = 0;
  for (int t = 0; t < nt; ++t) {
    if (t + 1 < nt) {  // issue next-tile global loads (latency hides under compute)
      const float* xn = Xp + (size_t)(t + 1) * 16;
      const float* wn = Wp + (size_t)(t + 1) * 16;
      ra0 = *(const f32x4*)(xn);
      ra1 = *(const f32x4*)(xn + 4);
      rb0 = *(const f32x4*)(wn);
      rb1 = *(const f32x4*)(wn + 4);
    }
#pragma unroll
    for (int k = 0; k < 16; ++k) {
      f32x4 a0 = *(const f32x4*)&As[buf][k][ty * 4];
      f32x4 a1 = *(const f32x4*)&As[buf][k][64 + ty * 4];
      f32x4 b0 = *(const f32x4*)&Bs[buf][k][tx * 4];
      f32x4 b1 = *(const f32x4*)&Bs[buf][k][64 + tx * 4];
#pragma unroll
      for (int i = 0; i < 4; ++i) {
        acc[i][0]     += a0[i] * b0;
        acc[i][1]     += a0[i] * b1;
        acc[i + 4][0] += a1[i] * b0;
        acc[i + 4][1] += a1[i] * b1;
      }
    }
    if (t + 1 < nt) {  // write prefetched tile into the other buffer
      int nb = buf ^ 1;
#pragma unroll
      for (int j = 0; j < 4; ++j) {
        As[nb][lk + j][lr] = ra0[j];  As[nb][lk + 4 + j][lr] = ra1[j];
        Bs[nb][lk + j][lr] = rb0[j];  Bs[nb][lk + 4 + j][lr] = rb1[j];
      }
    }
    __syncthreads();
    buf ^= 1;
  }

#pragma unroll
  for (int i = 0; i < 8; ++i) {
    int mr = m0 + ((i < 4) ? (ty * 4 + i) : (64 + ty * 4 + i - 4));
#pragma unroll
    for (int jb = 0; jb < 2; ++jb) {
      int nc = n0 + jb * 64 + tx * 4;
      f32x4 bz = *(const f32x4*)(bias + nc);
      f32x4 o4 = acc[i][jb] + bz;
      if (RELU) {
        o4[0] = fmaxf(o4[0], 0.f); o4[1] = fmaxf(o4[1], 0.f);
        o4[2] = fmaxf(o4[2], 0.f); o4[3] = fmaxf(o4[3], 0.f);
      }
      *(f32x4*)(out + (size_t)mr * N + nc) = o4;
    }
  }
}

// ---------------- attention S=256: one block per (batch,head), 256 thr ----------
__global__ __launch_bounds__(256, 2) void k_attn256(const float* __restrict__ qkv,
    float* __restrict__ o, int b0) {
  __shared__ f32x4 Ks[256 * 8];
  __shared__ f32x4 Vs[256 * 8];
  int bl = blockIdx.x >> 3, h = blockIdx.x & 7;
  int tid = threadIdx.x;
  const float* base = qkv + (size_t)bl * 256 * 768;
  int hc = h * 32;
  for (int idx = tid; idx < 2048; idx += 256) {
    int s = idx >> 3, w = idx & 7;
    Ks[idx] = *(const f32x4*)(base + (size_t)s * 768 + 256 + hc + w * 4);
    Vs[idx] = *(const f32x4*)(base + (size_t)s * 768 + 512 + hc + w * 4);
  }
  __syncthreads();
  f32x4 q[8], acc[8];
  const float* qp = base + (size_t)tid * 768 + hc;
#pragma unroll
  for (int w = 0; w < 8; ++w) { q[w] = *(const f32x4*)(qp + 4 * w); acc[w] = 0.f; }
  float m = -1e30f, l = 0.f;
  const float scale = 0.17677669529663687f;
  for (int j = 0; j < 256; ++j) {
    f32x4 d4 = q[0] * Ks[j * 8];
#pragma unroll
    for (int w = 1; w < 8; ++w) d4 += q[w] * Ks[j * 8 + w];
    float s_ = (d4[0] + d4[1] + d4[2] + d4[3]) * scale;
    float mn = fmaxf(m, s_);
    float p = __expf(s_ - mn);
    if (mn > m) {
      float al = __expf(m - mn);
      l *= al;
#pragma unroll
      for (int w = 0; w < 8; ++w) acc[w] *= al;
      m = mn;
    }
    l += p;
#pragma unroll
    for (int w = 0; w < 8; ++w) acc[w] += p * Vs[j * 8 + w];
  }
  float inv = 1.f / l;
  float* op = o + ((size_t)(b0 + bl) * 256 + tid) * DMODEL + hc;
#pragma unroll
  for (int w = 0; w < 8; ++w) *(f32x4*)(op + 4 * w) = acc[w] * inv;
}

// ---------------- attention S=32: one block per batch, thread=(head,row) --------
__global__ __launch_bounds__(256, 2) void k_attn32(const float* __restrict__ qkv,
    float* __restrict__ o, int b0) {
  __shared__ f32x4 Ks[32 * 64];  // [s][c], c = (h*32+e)/4
  __shared__ f32x4 Vs[32 * 64];
  int bl = blockIdx.x;
  int tid = threadIdx.x;
  const float* base = qkv + (size_t)bl * 32 * 768;
  for (int idx = tid; idx < 2048; idx += 256) {
    int s = idx >> 6, c = idx & 63;
    Ks[idx] = *(const f32x4*)(base + (size_t)s * 768 + 256 + c * 4);
    Vs[idx] = *(const f32x4*)(base + (size_t)s * 768 + 512 + c * 4);
  }
  __syncthreads();
  int h = tid >> 5, row = tid & 31;
  int hc = h * 32;
  f32x4 q[8], acc[8];
  const float* qp = base + (size_t)row * 768 + hc;
#pragma unroll
  for (int w = 0; w < 8; ++w) { q[w] = *(const f32x4*)(qp + 4 * w); acc[w] = 0.f; }
  float m = -1e30f, l = 0.f;
  const float scale = 0.17677669529663687f;
  for (int j = 0; j < 32; ++j) {
    const f32x4* kr = &Ks[j * 64 + h * 8];
    f32x4 d4 = q[0] * kr[0];
#pragma unroll
    for (int w = 1; w < 8; ++w) d4 += q[w] * kr[w];
    float s_ = (d4[0] + d4[1] + d4[2] + d4[3]) * scale;
    float mn = fmaxf(m, s_);
    float p = __expf(s_ - mn);
    if (mn > m) {
      float al = __expf(m - mn);
      l *= al;
#pragma unroll
      for (int w = 0; w < 8; ++w) acc[w] *= al;
      m = mn;
    }
    l += p;
    const f32x4* vr = &Vs[j * 64 + h * 8];
#pragma unroll
    for (int w = 0; w < 8; ++w) acc[w] += p * vr[w];
  }
  float inv = 1.f / l;
  float* op = o + ((size_t)(b0 + bl) * 32 + row) * DMODEL + hc;
#pragma unroll
  for (int w = 0; w < 8; ++w) *(f32x4*)(op + 4 * w) = acc[w] * inv;
}

// ---------------- residual add + LayerNorm, one wave per token ----------------
__global__ __launch_bounds__(64) void k_addln(float* __restrict__ x,
    const float* __restrict__ t, const float* __restrict__ sc,
    const float* __restrict__ bi) {
  size_t tok = blockIdx.x;
  int tid = threadIdx.x;
  f32x4 xv = *(const f32x4*)(x + tok * 256 + tid * 4);
  f32x4 tv = *(const f32x4*)(t + tok * 256 + tid * 4);
  f32x4 v = xv + tv;
  float s1 = v[0] + v[1] + v[2] + v[3];
#pragma unroll
  for (int o = 32; o > 0; o >>= 1) s1 += __shfl_xor(s1, o);
  float mean = s1 * (1.f / 256.f);
  f32x4 d = v - mean;
  float s2 = d[0] * d[0] + d[1] * d[1] + d[2] * d[2] + d[3] * d[3];
#pragma unroll
  for (int o = 32; o > 0; o >>= 1) s2 += __shfl_xor(s2, o);
  float rs = rsqrtf(s2 * (1.f / 256.f) + 1e-5f);
  f32x4 s4 = *(const f32x4*)(sc + tid * 4);
  f32x4 b4 = *(const f32x4*)(bi + tid * 4);
  f32x4 ov = d * rs * s4 + b4;
  *(f32x4*)(x + tok * 256 + tid * 4) = ov;
}

// ---------------- fused scoring ----------------
__global__ __launch_bounds__(256) void k_score(
    const int* __restrict__ qids, const int* __restrict__ dids,
    const float* __restrict__ emb, const float* __restrict__ xq,
    const float* __restrict__ xd, const float* __restrict__ a_ptr,
    const float* __restrict__ mlp_w, float* __restrict__ out) {
  __shared__ float qmix[32 * 256];
  __shared__ float qks[32 * 11];
  __shared__ float qmask_s[32];
  int b = blockIdx.x, tid = threadIdx.x;
  float av = a_ptr[0], aw = 1.f - av;
  for (int q = 0; q < 32; ++q) {
    int qid = qids[b * 32 + q];
    float qm = qid > 0 ? 1.f : 0.f;
    float ev = emb[(size_t)qid * 256 + tid];
    float xv = xq[((size_t)b * 32 + q) * 256 + tid];
    qmix[q * 256 + tid] = (av * ev + aw * xv) * qm;
    if (tid == 0) qmask_s[q] = qm;
  }
  for (int i = tid; i < 352; i += 256) qks[i] = 0.f;
  __syncthreads();
  int j = tid;
  int did = dids[b * 256 + j];
  float dmask = did > 0 ? 1.f : 0.f;
  float sim[32];
#pragma unroll
  for (int q = 0; q < 32; ++q) sim[q] = 0.f;
  const f32x4* de = (const f32x4*)(emb + (size_t)did * 256);
  const f32x4* dxp = (const f32x4*)(xd + ((size_t)b * 256 + j) * 256);
  for (int c = 0; c < 4; ++c) {
    f32x4 dreg[16];
#pragma unroll
    for (int w = 0; w < 16; ++w) dreg[w] = av * de[c * 16 + w] + aw * dxp[c * 16 + w];
#pragma unroll
    for (int q = 0; q < 32; ++q) {
      const f32x4* qp = (const f32x4*)&qmix[q * 256 + c * 64];
      f32x4 d4 = qp[0] * dreg[0];
#pragma unroll
      for (int w = 1; w < 16; ++w) d4 += qp[w] * dreg[w];
      sim[q] += d4[0] + d4[1] + d4[2] + d4[3];
    }
  }
  const float MU[11] = {1.f, 0.9f, 0.7f, 0.5f, 0.3f, 0.1f, -0.1f, -0.3f, -0.5f, -0.7f, -0.9f};
  const float IC[11] = {5e7f, 50.f, 50.f, 50.f, 50.f, 50.f, 50.f, 50.f, 50.f, 50.f, 50.f};
  for (int q = 0; q < 32; ++q) {
    float s = sim[q];
    float f = dmask * qmask_s[q];
#pragma unroll
    for (int k = 0; k < 11; ++k) {
      float d_ = s - MU[k];
      float v = expf(-d_ * d_ * IC[k]) * f;
#pragma unroll
      for (int o = 32; o > 0; o >>= 1) v += __shfl_xor(v, o);
      if ((tid & 63) == 0) atomicAdd(&qks[q * 11 + k], v);
    }
  }
  __syncthreads();
  if (tid < 32) {
    float qm = qmask_s[tid];
    float p = 0.f;
#pragma unroll
    for (int k = 0; k < 11; ++k) {
      float qv = qks[tid * 11 + k];
      p += mlp_w[k] * (qm * logf(fmaxf(qv, 1e-10f)) + qv * (1.f / 256.f));
    }
#pragma unroll
    for (int o = 16; o > 0; o >>= 1) p += __shfl_xor(p, o);
    if (tid == 0) out[b] = p;
  }
}

// ---------------- host-side encoder schedule ----------------
static void run_encoder(float* x, int S, int B, int CB, int FC,
    const float* Wqkv, const float* bqkv, const float* Wo, const float* bo,
    const float* l1s, const float* l1b, const float* W1, const float* b1,
    const float* W2, const float* b2, const float* l2s, const float* l2b,
    float* qkv, float* t0, float* t1, float* h, hipStream_t stream) {
  int tokens = B * S;
  int nchunk = B / CB;
  for (int l = 0; l < 2; ++l) {
    const float* wq = Wqkv + (size_t)l * 768 * 256;
    const float* bq = bqkv + l * 768;
    const float* wo = Wo + (size_t)l * 256 * 256;
    const float* bo_ = bo + l * 256;
    const float* w1 = W1 + (size_t)l * 2048 * 256;
    const float* b1_ = b1 + l * 2048;
    const float* w2 = W2 + (size_t)l * 256 * 2048;
    const float* b2_ = b2 + l * 256;
    for (int c = 0; c < nchunk; ++c) {
      float* xc = x + (size_t)c * CB * S * 256;
      int Mc = CB * S;
      k_gemm<false><<<dim3(768 / 128, Mc / 128), 256, 0, stream>>>(xc, wq, bq, qkv, Mc, 768, 256);
      if (S == 256)
        k_attn256<<<CB * 8, 256, 0, stream>>>(qkv, t0, c * CB);
      else
        k_attn32<<<CB, 256, 0, stream>>>(qkv, t0, c * CB);
    }
    k_gemm<false><<<dim3(2, tokens / 128), 256, 0, stream>>>(t0, wo, bo_, t1, tokens, 256, 256);
    k_addln<<<tokens, 64, 0, stream>>>(x, t1, l1s + l * 256, l1b + l * 256);
    for (int f = 0; f < tokens; f += FC) {
      int Mc = (tokens - f < FC) ? (tokens - f) : FC;
      k_gemm<true><<<dim3(16, Mc / 128), 256, 0, stream>>>(x + (size_t)f * 256, w1, b1_, h, Mc, 2048, 256);
      k_gemm<false><<<dim3(2, Mc / 128), 256, 0, stream>>>(h, w2, b2_, t1 + (size_t)f * 256, Mc, 256, 2048);
    }
    k_addln<<<tokens, 64, 0, stream>>>(x, t1, l2s + l * 256, l2b + l * 256);
  }
}

extern "C" void kernel_launch(void* const* d_in, const int* in_sizes, int n_in,
                              void* d_out, int out_size, void* d_ws, size_t ws_size,
                              hipStream_t stream) {
  const int* qids = (const int*)d_in[0];
  const int* dids = (const int*)d_in[1];
  const float* emb = (const float*)d_in[2];
  const float* a = (const float*)d_in[3];
  const float* mlp_w = (const float*)d_in[4];
  const float* Wqkv = (const float*)d_in[5];
  const float* bqkv = (const float*)d_in[6];
  const float* Wo = (const float*)d_in[7];
  const float* bo = (const float*)d_in[8];
  const float* l1s = (const float*)d_in[9];
  const float* l1b = (const float*)d_in[10];
  const float* W1 = (const float*)d_in[11];
  const float* b1 = (const float*)d_in[12];
  const float* W2 = (const float*)d_in[13];
  const float* b2 = (const float*)d_in[14];
  const float* l2s = (const float*)d_in[15];
  const float* l2b = (const float*)d_in[16];
  float* out = (float*)d_out;
  float* ws = (float*)d_ws;

  size_t wsf = ws_size / 4;
  float* xq = ws;                    // 2,097,152
  float* xd = xq + 2097152;          // 16,777,216
  float* t0 = xd + 16777216;
  float* t1 = t0 + 16777216;
  float* qkv = t1 + 16777216;
  const size_t fixed = 2097152 + 3 * 16777216UL;

  // pick largest (CB, FC) that fits: bigger grids -> better occupancy
  const int cbs[] = {256, 128, 128, 64, 64, 32, 16, 8, 8};
  const int fcs[] = {65536, 65536, 32768, 32768, 16384, 16384, 8192, 4096, 2048};
  int CB = 8, FC = 2048;
  for (int i = 0; i < 9; ++i) {
    if (fixed + (size_t)cbs[i] * 196608 + (size_t)fcs[i] * 2048 <= wsf) {
      CB = cbs[i]; FC = fcs[i]; break;
    }
  }
  float* h = qkv + (size_t)CB * 196608;

  k_embed<<<256 * 32, 256, 0, stream>>>(qids, emb, xq, 32);
  k_embed<<<256 * 256, 256, 0, stream>>>(dids, emb, xd, 256);

  run_encoder(xd, 256, 256, CB, FC, Wqkv, bqkv, Wo, bo, l1s, l1b, W1, b1,
              W2, b2, l2s, l2b, qkv, t0, t1, h, stream);
  int CBq = CB * 8; if (CBq > 256) CBq = 256;
  run_encoder(xq, 32, 256, CBq, FC, Wqkv, bqkv, Wo, bo, l1s, l1b, W1, b1,
              W2, b2, l2s, l2b, qkv, t0, t1, h, stream);

  k_score<<<256, 256, 0, stream>>>(qids, dids, emb, xq, xd, a, mlp_w, out);
}

// Round 3
// 22714.760 us; speedup vs baseline: 2.8477x; 2.8477x over previous
//
#include <hip/hip_runtime.h>
#include <math.h>

// KNRM-style ranker, fp32 end-to-end (kernel-0 sigma=1e-4 makes sim
// precision-critical: bf16/MFMA would flip exp-window hits).
// R3: full revert of GEMM/attention/chunking to the R1 known-good code
// (22.8ms; W1 GEMM ~64 TF, at the LDS-BW roofline for 8x8 micro-tiles).
// Only deltas vs R1: k_embed and k_addln repacked 4 tokens per 256-thread
// block (1 wave/token) to cut block counts 4x (launch overhead).

#define DMODEL 256

// ---------------- embed + positional encoding (4 tokens / block) ------------
// wave w of block handles token blockIdx.x*4+w; lane handles 4 d's.
__global__ __launch_bounds__(256) void k_embed(const int* __restrict__ ids,
    const float* __restrict__ emb, float* __restrict__ out_x, int S) {
  int tid = threadIdx.x;
  int tok = blockIdx.x * 4 + (tid >> 6);
  int lane = tid & 63;
  int d0 = lane * 4;
  int id = ids[tok];
  float m = id > 0 ? 1.f : 0.f;
  const float* ep = emb + (size_t)id * DMODEL + d0;
  float4 e = *(const float4*)ep;
  int s = tok % S;
  float o[4];
  float ev[4] = {e.x, e.y, e.z, e.w};
#pragma unroll
  for (int j = 0; j < 4; ++j) {
    int d = d0 + j;
    int i2 = d & ~1;
    float freq = expf((float)i2 * (-9.210340371976184f / 256.f));
    float ang = (float)s * freq;
    float pe = (d & 1) ? cosf(ang) : sinf(ang);
    o[j] = 2.f * ev[j] * m + pe;
  }
  *(float4*)(out_x + (size_t)tok * DMODEL + d0) = *(float4*)o;
}

// ---------------- fp32 GEMM (exact R1 code): out = X @ W^T + bias ----------
template<bool RELU>
__global__ __launch_bounds__(256) void k_gemm(const float* __restrict__ X,
    const float* __restrict__ W, const float* __restrict__ bias,
    float* __restrict__ out, int M, int N, int K) {
  __shared__ float As[16][128];
  __shared__ float Bs[16][128];
  int n0 = blockIdx.x * 128;
  int m0 = blockIdx.y * 128;
  int tid = threadIdx.x;
  int tx = tid & 15, ty = tid >> 4;
  float acc[8][8];
#pragma unroll
  for (int i = 0; i < 8; ++i)
#pragma unroll
    for (int j = 0; j < 8; ++j) acc[i][j] = 0.f;
  int lr = tid >> 1;
  int lk = (tid & 1) << 3;
  const float* Xp = X + (size_t)(m0 + lr) * K + lk;
  const float* Wp = W + (size_t)(n0 + lr) * K + lk;
  for (int kt = 0; kt < K; kt += 16) {
    float4 a0 = *(const float4*)(Xp + kt);
    float4 a1 = *(const float4*)(Xp + kt + 4);
    float4 b0 = *(const float4*)(Wp + kt);
    float4 b1 = *(const float4*)(Wp + kt + 4);
    __syncthreads();
    As[lk + 0][lr] = a0.x; As[lk + 1][lr] = a0.y; As[lk + 2][lr] = a0.z; As[lk + 3][lr] = a0.w;
    As[lk + 4][lr] = a1.x; As[lk + 5][lr] = a1.y; As[lk + 6][lr] = a1.z; As[lk + 7][lr] = a1.w;
    Bs[lk + 0][lr] = b0.x; Bs[lk + 1][lr] = b0.y; Bs[lk + 2][lr] = b0.z; Bs[lk + 3][lr] = b0.w;
    Bs[lk + 4][lr] = b1.x; Bs[lk + 5][lr] = b1.y; Bs[lk + 6][lr] = b1.z; Bs[lk + 7][lr] = b1.w;
    __syncthreads();
#pragma unroll
    for (int k = 0; k < 16; ++k) {
      float av[8], bv[8];
      *(float4*)&av[0] = *(const float4*)&As[k][ty * 4];
      *(float4*)&av[4] = *(const float4*)&As[k][64 + ty * 4];
      *(float4*)&bv[0] = *(const float4*)&Bs[k][tx * 4];
      *(float4*)&bv[4] = *(const float4*)&Bs[k][64 + tx * 4];
#pragma unroll
      for (int i = 0; i < 8; ++i)
#pragma unroll
        for (int j = 0; j < 8; ++j)
          acc[i][j] += av[i] * bv[j];
    }
  }
#pragma unroll
  for (int i = 0; i < 8; ++i) {
    int mr = m0 + ((i < 4) ? (ty * 4 + i) : (64 + ty * 4 + i - 4));
#pragma unroll
    for (int jb = 0; jb < 2; ++jb) {
      int nc = n0 + jb * 64 + tx * 4;
      float4 bz = *(const float4*)(bias + nc);
      float4 o4;
      o4.x = acc[i][jb * 4 + 0] + bz.x;
      o4.y = acc[i][jb * 4 + 1] + bz.y;
      o4.z = acc[i][jb * 4 + 2] + bz.z;
      o4.w = acc[i][jb * 4 + 3] + bz.w;
      if (RELU) {
        o4.x = fmaxf(o4.x, 0.f); o4.y = fmaxf(o4.y, 0.f);
        o4.z = fmaxf(o4.z, 0.f); o4.w = fmaxf(o4.w, 0.f);
      }
      *(float4*)(out + (size_t)mr * N + nc) = o4;
    }
  }
}

// ---------------- fused attention (exact R1 code) ----------------
template<int NR>
__global__ __launch_bounds__(128) void k_attn(const float* __restrict__ qkv,
    float* __restrict__ o, int S, int b0) {
  __shared__ float Ks[256 * 32];
  __shared__ float Vs[256 * 32];
  int bl = blockIdx.x >> 3;
  int h = blockIdx.x & 7;
  int tid = threadIdx.x;
  const float* base = qkv + (size_t)bl * S * 768;
  int hc = h * 32;
  for (int f = tid; f < S * 32; f += 128) {
    int s = f >> 5, e = f & 31;
    Ks[f] = base[(size_t)s * 768 + 256 + hc + e];
    Vs[f] = base[(size_t)s * 768 + 512 + hc + e];
  }
  __syncthreads();
  if (tid >= S) return;
  const float scale = 0.17677669529663687f;
  float q[NR][32], acc[NR][32], m[NR], l[NR];
#pragma unroll
  for (int r = 0; r < NR; ++r) {
    int row = tid + 128 * r;
    const float4* qp = (const float4*)(base + (size_t)row * 768 + hc);
#pragma unroll
    for (int w = 0; w < 8; ++w) {
      float4 t = qp[w];
      q[r][4 * w] = t.x; q[r][4 * w + 1] = t.y; q[r][4 * w + 2] = t.z; q[r][4 * w + 3] = t.w;
    }
    m[r] = -1e30f; l[r] = 0.f;
#pragma unroll
    for (int e = 0; e < 32; ++e) acc[r][e] = 0.f;
  }
  for (int j = 0; j < S; ++j) {
    float kv[32];
    const float4* kp = (const float4*)&Ks[j * 32];
#pragma unroll
    for (int w = 0; w < 8; ++w) {
      float4 t = kp[w];
      kv[4 * w] = t.x; kv[4 * w + 1] = t.y; kv[4 * w + 2] = t.z; kv[4 * w + 3] = t.w;
    }
    float p[NR];
#pragma unroll
    for (int r = 0; r < NR; ++r) {
      float dot = 0.f;
#pragma unroll
      for (int e = 0; e < 32; ++e) dot += q[r][e] * kv[e];
      float s_ = dot * scale;
      float mn = fmaxf(m[r], s_);
      p[r] = __expf(s_ - mn);
      if (mn > m[r]) {
        float al = __expf(m[r] - mn);
        l[r] *= al;
#pragma unroll
        for (int e = 0; e < 32; ++e) acc[r][e] *= al;
        m[r] = mn;
      }
      l[r] += p[r];
    }
    const float4* vp = (const float4*)&Vs[j * 32];
#pragma unroll
    for (int w = 0; w < 8; ++w) {
      float4 t = vp[w];
#pragma unroll
      for (int r = 0; r < NR; ++r) {
        acc[r][4 * w]     += p[r] * t.x;
        acc[r][4 * w + 1] += p[r] * t.y;
        acc[r][4 * w + 2] += p[r] * t.z;
        acc[r][4 * w + 3] += p[r] * t.w;
      }
    }
  }
#pragma unroll
  for (int r = 0; r < NR; ++r) {
    int row = tid + 128 * r;
    float inv = 1.f / l[r];
    float4* op = (float4*)(o + ((size_t)(b0 + bl) * S + row) * DMODEL + hc);
#pragma unroll
    for (int w = 0; w < 8; ++w) {
      float4 t;
      t.x = acc[r][4 * w] * inv;     t.y = acc[r][4 * w + 1] * inv;
      t.z = acc[r][4 * w + 2] * inv; t.w = acc[r][4 * w + 3] * inv;
      op[w] = t;
    }
  }
}

// ---------------- residual add + LayerNorm (4 tokens / 256-thr block) --------
__global__ __launch_bounds__(256) void k_addln(float* __restrict__ x,
    const float* __restrict__ t, const float* __restrict__ sc,
    const float* __restrict__ bi) {
  int tid = threadIdx.x;
  size_t tok = (size_t)blockIdx.x * 4 + (tid >> 6);
  int lane = tid & 63;
  float4 xv = *(const float4*)(x + tok * 256 + lane * 4);
  float4 tv = *(const float4*)(t + tok * 256 + lane * 4);
  float4 v;
  v.x = xv.x + tv.x; v.y = xv.y + tv.y; v.z = xv.z + tv.z; v.w = xv.w + tv.w;
  float s1 = v.x + v.y + v.z + v.w;
#pragma unroll
  for (int o = 32; o > 0; o >>= 1) s1 += __shfl_xor(s1, o);
  float mean = s1 * (1.f / 256.f);
  float dx = v.x - mean, dy = v.y - mean, dz = v.z - mean, dw = v.w - mean;
  float s2 = dx * dx + dy * dy + dz * dz + dw * dw;
#pragma unroll
  for (int o = 32; o > 0; o >>= 1) s2 += __shfl_xor(s2, o);
  float rs = rsqrtf(s2 * (1.f / 256.f) + 1e-5f);
  float4 s4 = *(const float4*)(sc + lane * 4);
  float4 b4 = *(const float4*)(bi + lane * 4);
  float4 ov;
  ov.x = dx * rs * s4.x + b4.x;
  ov.y = dy * rs * s4.y + b4.y;
  ov.z = dz * rs * s4.z + b4.z;
  ov.w = dw * rs * s4.w + b4.w;
  *(float4*)(x + tok * 256 + lane * 4) = ov;
}

// ---------------- fused scoring (exact R1 code) ----------------
__global__ __launch_bounds__(256) void k_score(
    const int* __restrict__ qids, const int* __restrict__ dids,
    const float* __restrict__ emb, const float* __restrict__ xq,
    const float* __restrict__ xd, const float* __restrict__ a_ptr,
    const float* __restrict__ mlp_w, float* __restrict__ out) {
  __shared__ float qmix[32 * 256];
  __shared__ float qks[32 * 11];
  __shared__ float qmask_s[32];
  int b = blockIdx.x, tid = threadIdx.x;
  float av = a_ptr[0], aw = 1.f - av;
  for (int q = 0; q < 32; ++q) {
    int qid = qids[b * 32 + q];
    float qm = qid > 0 ? 1.f : 0.f;
    float ev = emb[(size_t)qid * 256 + tid];
    float xv = xq[((size_t)b * 32 + q) * 256 + tid];
    qmix[q * 256 + tid] = (av * ev + aw * xv) * qm;
    if (tid == 0) qmask_s[q] = qm;
  }
  for (int i = tid; i < 352; i += 256) qks[i] = 0.f;
  __syncthreads();
  int j = tid;
  int did = dids[b * 256 + j];
  float dmask = did > 0 ? 1.f : 0.f;
  float sim[32];
#pragma unroll
  for (int q = 0; q < 32; ++q) sim[q] = 0.f;
  const float4* de = (const float4*)(emb + (size_t)did * 256);
  const float4* dxp = (const float4*)(xd + ((size_t)b * 256 + j) * 256);
  for (int c = 0; c < 4; ++c) {
    float4 dreg[16];
#pragma unroll
    for (int w = 0; w < 16; ++w) {
      float4 e = de[c * 16 + w], x = dxp[c * 16 + w];
      dreg[w].x = av * e.x + aw * x.x;
      dreg[w].y = av * e.y + aw * x.y;
      dreg[w].z = av * e.z + aw * x.z;
      dreg[w].w = av * e.w + aw * x.w;
    }
#pragma unroll
    for (int q = 0; q < 32; ++q) {
      const float4* qp = (const float4*)&qmix[q * 256 + c * 64];
      float d_ = 0.f;
#pragma unroll
      for (int w = 0; w < 16; ++w) {
        float4 t = qp[w];
        d_ += t.x * dreg[w].x + t.y * dreg[w].y + t.z * dreg[w].z + t.w * dreg[w].w;
      }
      sim[q] += d_;
    }
  }
  const float MU[11] = {1.f, 0.9f, 0.7f, 0.5f, 0.3f, 0.1f, -0.1f, -0.3f, -0.5f, -0.7f, -0.9f};
  const float IC[11] = {5e7f, 50.f, 50.f, 50.f, 50.f, 50.f, 50.f, 50.f, 50.f, 50.f, 50.f};
  for (int q = 0; q < 32; ++q) {
    float s = sim[q];
    float f = dmask * qmask_s[q];
#pragma unroll
    for (int k = 0; k < 11; ++k) {
      float d_ = s - MU[k];
      float v = expf(-d_ * d_ * IC[k]) * f;
#pragma unroll
      for (int o = 32; o > 0; o >>= 1) v += __shfl_xor(v, o);
      if ((tid & 63) == 0) atomicAdd(&qks[q * 11 + k], v);
    }
  }
  __syncthreads();
  if (tid < 32) {
    float qm = qmask_s[tid];
    float p = 0.f;
#pragma unroll
    for (int k = 0; k < 11; ++k) {
      float qv = qks[tid * 11 + k];
      p += mlp_w[k] * (qm * logf(fmaxf(qv, 1e-10f)) + qv * (1.f / 256.f));
    }
#pragma unroll
    for (int o = 16; o > 0; o >>= 1) p += __shfl_xor(p, o);
    if (tid == 0) out[b] = p;
  }
}

// ---------------- host-side encoder schedule (exact R1 code) ----------------
static void run_encoder(float* x, int S, int B, int CB, int FC,
    const float* Wqkv, const float* bqkv, const float* Wo, const float* bo,
    const float* l1s, const float* l1b, const float* W1, const float* b1,
    const float* W2, const float* b2, const float* l2s, const float* l2b,
    float* qkv, float* t0, float* t1, float* h, hipStream_t stream) {
  int tokens = B * S;
  int nchunk = B / CB;
  for (int l = 0; l < 2; ++l) {
    const float* wq = Wqkv + (size_t)l * 768 * 256;
    const float* bq = bqkv + l * 768;
    const float* wo = Wo + (size_t)l * 256 * 256;
    const float* bo_ = bo + l * 256;
    const float* w1 = W1 + (size_t)l * 2048 * 256;
    const float* b1_ = b1 + l * 2048;
    const float* w2 = W2 + (size_t)l * 256 * 2048;
    const float* b2_ = b2 + l * 256;
    for (int c = 0; c < nchunk; ++c) {
      float* xc = x + (size_t)c * CB * S * 256;
      int Mc = CB * S;
      k_gemm<false><<<dim3(768 / 128, Mc / 128), 256, 0, stream>>>(xc, wq, bq, qkv, Mc, 768, 256);
      if (S == 256)
        k_attn<2><<<CB * 8, 128, 0, stream>>>(qkv, t0, S, c * CB);
      else
        k_attn<1><<<CB * 8, 128, 0, stream>>>(qkv, t0, S, c * CB);
    }
    k_gemm<false><<<dim3(2, tokens / 128), 256, 0, stream>>>(t0, wo, bo_, t1, tokens, 256, 256);
    k_addln<<<tokens / 4, 256, 0, stream>>>(x, t1, l1s + l * 256, l1b + l * 256);
    for (int f = 0; f < tokens; f += FC) {
      int Mc = (tokens - f < FC) ? (tokens - f) : FC;
      k_gemm<true><<<dim3(16, Mc / 128), 256, 0, stream>>>(x + (size_t)f * 256, w1, b1_, h, Mc, 2048, 256);
      k_gemm<false><<<dim3(2, Mc / 128), 256, 0, stream>>>(h, w2, b2_, t1 + (size_t)f * 256, Mc, 256, 2048);
    }
    k_addln<<<tokens / 4, 256, 0, stream>>>(x, t1, l2s + l * 256, l2b + l * 256);
  }
}

extern "C" void kernel_launch(void* const* d_in, const int* in_sizes, int n_in,
                              void* d_out, int out_size, void* d_ws, size_t ws_size,
                              hipStream_t stream) {
  const int* qids = (const int*)d_in[0];
  const int* dids = (const int*)d_in[1];
  const float* emb = (const float*)d_in[2];
  const float* a = (const float*)d_in[3];
  const float* mlp_w = (const float*)d_in[4];
  const float* Wqkv = (const float*)d_in[5];
  const float* bqkv = (const float*)d_in[6];
  const float* Wo = (const float*)d_in[7];
  const float* bo = (const float*)d_in[8];
  const float* l1s = (const float*)d_in[9];
  const float* l1b = (const float*)d_in[10];
  const float* W1 = (const float*)d_in[11];
  const float* b1 = (const float*)d_in[12];
  const float* W2 = (const float*)d_in[13];
  const float* b2 = (const float*)d_in[14];
  const float* l2s = (const float*)d_in[15];
  const float* l2b = (const float*)d_in[16];
  float* out = (float*)d_out;
  float* ws = (float*)d_ws;

  size_t wsf = ws_size / 4;
  float* xq = ws;                    // 256*32*256
  float* xd = xq + 2097152;          // 256*256*256
  float* t0 = xd + 16777216;
  float* t1 = t0 + 16777216;
  float* qkv = t1 + 16777216;
  const size_t fixed = 2097152 + 3 * 16777216UL;
  int CB = 64, FC = 16384;  // R1 config
  while (CB > 8 && fixed + (size_t)CB * 196608 + (size_t)FC * 2048 > wsf) CB >>= 1;
  while (FC > 2048 && fixed + (size_t)CB * 196608 + (size_t)FC * 2048 > wsf) FC >>= 1;
  float* h = qkv + (size_t)CB * 196608;

  k_embed<<<256 * 32 / 4, 256, 0, stream>>>(qids, emb, xq, 32);
  k_embed<<<256 * 256 / 4, 256, 0, stream>>>(dids, emb, xd, 256);

  run_encoder(xd, 256, 256, CB, FC, Wqkv, bqkv, Wo, bo, l1s, l1b, W1, b1,
              W2, b2, l2s, l2b, qkv, t0, t1, h, stream);
  int CBq = CB * 8; if (CBq > 256) CBq = 256;
  run_encoder(xq, 32, 256, CBq, FC, Wqkv, bqkv, Wo, bo, l1s, l1b, W1, b1,
              W2, b2, l2s, l2b, qkv, t0, t1, h, stream);

  k_score<<<256, 256, 0, stream>>>(qids, dids, emb, xq, xd, a, mlp_w, out);
}

// Round 4
// 22385.417 us; speedup vs baseline: 2.8896x; 1.0147x over previous
//
#include <hip/hip_runtime.h>
#include <math.h>

// KNRM-style ranker, fp32 end-to-end (kernel-0 sigma=1e-4 makes sim
// precision-critical: bf16/MFMA would flip exp-window hits).
// R4 vs R3 (22.7ms baseline): GEMM gets static ping-pong double-buffering
// (1 barrier/tile, loads for t+1 hidden under compute of t), no VGPR cap
// (R2's 3x regression was launch_bounds(256,2) spilling acc to scratch).
// Config: try CB=256 (doc QKV/attn unchunked) with fallback to 394MB config.

#define DMODEL 256

// ---------------- embed + positional encoding (4 tokens / block) ------------
__global__ __launch_bounds__(256) void k_embed(const int* __restrict__ ids,
    const float* __restrict__ emb, float* __restrict__ out_x, int S) {
  int tid = threadIdx.x;
  int tok = blockIdx.x * 4 + (tid >> 6);
  int lane = tid & 63;
  int d0 = lane * 4;
  int id = ids[tok];
  float m = id > 0 ? 1.f : 0.f;
  const float* ep = emb + (size_t)id * DMODEL + d0;
  float4 e = *(const float4*)ep;
  int s = tok % S;
  float o[4];
  float ev[4] = {e.x, e.y, e.z, e.w};
#pragma unroll
  for (int j = 0; j < 4; ++j) {
    int d = d0 + j;
    int i2 = d & ~1;
    float freq = expf((float)i2 * (-9.210340371976184f / 256.f));
    float ang = (float)s * freq;
    float pe = (d & 1) ? cosf(ang) : sinf(ang);
    o[j] = 2.f * ev[j] * m + pe;
  }
  *(float4*)(out_x + (size_t)tok * DMODEL + d0) = *(float4*)o;
}

// ---------------- fp32 GEMM: out[M,N] = X[M,K] @ W[N,K]^T + bias (opt ReLU) --
// 128x128x16 tile, 256 threads, 8x8 micro (4+4 split).
// Ping-pong LDS double-buffer, static indices, 1 barrier per K-tile:
//   [buf0 ready] LOAD(t+1) ; COMP(buf0) ; WRITE(buf1) ; barrier
//                LOAD(t+2) ; COMP(buf1) ; WRITE(buf0) ; barrier
// Safety: any WRITE(bufX) is >=1 barrier after the last COMP(bufX).
// Requires M%128==0, N%128==0, (K/16) even (all shapes here comply).
template<bool RELU>
__global__ __launch_bounds__(256) void k_gemm(const float* __restrict__ X,
    const float* __restrict__ W, const float* __restrict__ bias,
    float* __restrict__ out, int M, int N, int K) {
  __shared__ float As[2][16][128];
  __shared__ float Bs[2][16][128];
  int n0 = blockIdx.x * 128;
  int m0 = blockIdx.y * 128;
  int tid = threadIdx.x;
  int tx = tid & 15, ty = tid >> 4;
  int lr = tid >> 1;
  int lk = (tid & 1) << 3;
  const float* Xp = X + (size_t)(m0 + lr) * K + lk;
  const float* Wp = W + (size_t)(n0 + lr) * K + lk;

  float acc[8][8];
#pragma unroll
  for (int i = 0; i < 8; ++i)
#pragma unroll
    for (int j = 0; j < 8; ++j) acc[i][j] = 0.f;

  float4 a0, a1, b0, b1;

#define GLOADT(KT) do { \
    a0 = *(const float4*)(Xp + (KT)); a1 = *(const float4*)(Xp + (KT) + 4); \
    b0 = *(const float4*)(Wp + (KT)); b1 = *(const float4*)(Wp + (KT) + 4); } while (0)

#define LWRITE(BUF) do { \
    As[BUF][lk + 0][lr] = a0.x; As[BUF][lk + 1][lr] = a0.y; \
    As[BUF][lk + 2][lr] = a0.z; As[BUF][lk + 3][lr] = a0.w; \
    As[BUF][lk + 4][lr] = a1.x; As[BUF][lk + 5][lr] = a1.y; \
    As[BUF][lk + 6][lr] = a1.z; As[BUF][lk + 7][lr] = a1.w; \
    Bs[BUF][lk + 0][lr] = b0.x; Bs[BUF][lk + 1][lr] = b0.y; \
    Bs[BUF][lk + 2][lr] = b0.z; Bs[BUF][lk + 3][lr] = b0.w; \
    Bs[BUF][lk + 4][lr] = b1.x; Bs[BUF][lk + 5][lr] = b1.y; \
    Bs[BUF][lk + 6][lr] = b1.z; Bs[BUF][lk + 7][lr] = b1.w; } while (0)

#define COMPT(BUF) do { \
    _Pragma("unroll") \
    for (int k = 0; k < 16; ++k) { \
      float av[8], bv[8]; \
      *(float4*)&av[0] = *(const float4*)&As[BUF][k][ty * 4]; \
      *(float4*)&av[4] = *(const float4*)&As[BUF][k][64 + ty * 4]; \
      *(float4*)&bv[0] = *(const float4*)&Bs[BUF][k][tx * 4]; \
      *(float4*)&bv[4] = *(const float4*)&Bs[BUF][k][64 + tx * 4]; \
      _Pragma("unroll") \
      for (int i = 0; i < 8; ++i) \
        _Pragma("unroll") \
        for (int j = 0; j < 8; ++j) \
          acc[i][j] += av[i] * bv[j]; \
    } } while (0)

  const int nt = K >> 4;  // even for all shapes used (16 or 128)
  GLOADT(0);
  LWRITE(0);
  __syncthreads();
  for (int t = 0; t < nt; t += 2) {
    int k1 = (t + 1) * 16;
    GLOADT(k1);            // hidden under COMPT(0)
    COMPT(0);
    LWRITE(1);
    __syncthreads();
    if (t + 2 < nt) {
      int k2 = (t + 2) * 16;
      GLOADT(k2);          // hidden under COMPT(1)
      COMPT(1);
      LWRITE(0);
    } else {
      COMPT(1);
    }
    __syncthreads();
  }
#undef GLOADT
#undef LWRITE
#undef COMPT

#pragma unroll
  for (int i = 0; i < 8; ++i) {
    int mr = m0 + ((i < 4) ? (ty * 4 + i) : (64 + ty * 4 + i - 4));
#pragma unroll
    for (int jb = 0; jb < 2; ++jb) {
      int nc = n0 + jb * 64 + tx * 4;
      float4 bz = *(const float4*)(bias + nc);
      float4 o4;
      o4.x = acc[i][jb * 4 + 0] + bz.x;
      o4.y = acc[i][jb * 4 + 1] + bz.y;
      o4.z = acc[i][jb * 4 + 2] + bz.z;
      o4.w = acc[i][jb * 4 + 3] + bz.w;
      if (RELU) {
        o4.x = fmaxf(o4.x, 0.f); o4.y = fmaxf(o4.y, 0.f);
        o4.z = fmaxf(o4.z, 0.f); o4.w = fmaxf(o4.w, 0.f);
      }
      *(float4*)(out + (size_t)mr * N + nc) = o4;
    }
  }
}

// ---------------- fused attention (exact R1/R3 code) ----------------
template<int NR>
__global__ __launch_bounds__(128) void k_attn(const float* __restrict__ qkv,
    float* __restrict__ o, int S, int b0) {
  __shared__ float Ks[256 * 32];
  __shared__ float Vs[256 * 32];
  int bl = blockIdx.x >> 3;
  int h = blockIdx.x & 7;
  int tid = threadIdx.x;
  const float* base = qkv + (size_t)bl * S * 768;
  int hc = h * 32;
  for (int f = tid; f < S * 32; f += 128) {
    int s = f >> 5, e = f & 31;
    Ks[f] = base[(size_t)s * 768 + 256 + hc + e];
    Vs[f] = base[(size_t)s * 768 + 512 + hc + e];
  }
  __syncthreads();
  if (tid >= S) return;
  const float scale = 0.17677669529663687f;
  float q[NR][32], acc[NR][32], m[NR], l[NR];
#pragma unroll
  for (int r = 0; r < NR; ++r) {
    int row = tid + 128 * r;
    const float4* qp = (const float4*)(base + (size_t)row * 768 + hc);
#pragma unroll
    for (int w = 0; w < 8; ++w) {
      float4 t = qp[w];
      q[r][4 * w] = t.x; q[r][4 * w + 1] = t.y; q[r][4 * w + 2] = t.z; q[r][4 * w + 3] = t.w;
    }
    m[r] = -1e30f; l[r] = 0.f;
#pragma unroll
    for (int e = 0; e < 32; ++e) acc[r][e] = 0.f;
  }
  for (int j = 0; j < S; ++j) {
    float kv[32];
    const float4* kp = (const float4*)&Ks[j * 32];
#pragma unroll
    for (int w = 0; w < 8; ++w) {
      float4 t = kp[w];
      kv[4 * w] = t.x; kv[4 * w + 1] = t.y; kv[4 * w + 2] = t.z; kv[4 * w + 3] = t.w;
    }
    float p[NR];
#pragma unroll
    for (int r = 0; r < NR; ++r) {
      float dot = 0.f;
#pragma unroll
      for (int e = 0; e < 32; ++e) dot += q[r][e] * kv[e];
      float s_ = dot * scale;
      float mn = fmaxf(m[r], s_);
      p[r] = __expf(s_ - mn);
      if (mn > m[r]) {
        float al = __expf(m[r] - mn);
        l[r] *= al;
#pragma unroll
        for (int e = 0; e < 32; ++e) acc[r][e] *= al;
        m[r] = mn;
      }
      l[r] += p[r];
    }
    const float4* vp = (const float4*)&Vs[j * 32];
#pragma unroll
    for (int w = 0; w < 8; ++w) {
      float4 t = vp[w];
#pragma unroll
      for (int r = 0; r < NR; ++r) {
        acc[r][4 * w]     += p[r] * t.x;
        acc[r][4 * w + 1] += p[r] * t.y;
        acc[r][4 * w + 2] += p[r] * t.z;
        acc[r][4 * w + 3] += p[r] * t.w;
      }
    }
  }
#pragma unroll
  for (int r = 0; r < NR; ++r) {
    int row = tid + 128 * r;
    float inv = 1.f / l[r];
    float4* op = (float4*)(o + ((size_t)(b0 + bl) * S + row) * DMODEL + hc);
#pragma unroll
    for (int w = 0; w < 8; ++w) {
      float4 t;
      t.x = acc[r][4 * w] * inv;     t.y = acc[r][4 * w + 1] * inv;
      t.z = acc[r][4 * w + 2] * inv; t.w = acc[r][4 * w + 3] * inv;
      op[w] = t;
    }
  }
}

// ---------------- residual add + LayerNorm (4 tokens / 256-thr block) --------
__global__ __launch_bounds__(256) void k_addln(float* __restrict__ x,
    const float* __restrict__ t, const float* __restrict__ sc,
    const float* __restrict__ bi) {
  int tid = threadIdx.x;
  size_t tok = (size_t)blockIdx.x * 4 + (tid >> 6);
  int lane = tid & 63;
  float4 xv = *(const float4*)(x + tok * 256 + lane * 4);
  float4 tv = *(const float4*)(t + tok * 256 + lane * 4);
  float4 v;
  v.x = xv.x + tv.x; v.y = xv.y + tv.y; v.z = xv.z + tv.z; v.w = xv.w + tv.w;
  float s1 = v.x + v.y + v.z + v.w;
#pragma unroll
  for (int o = 32; o > 0; o >>= 1) s1 += __shfl_xor(s1, o);
  float mean = s1 * (1.f / 256.f);
  float dx = v.x - mean, dy = v.y - mean, dz = v.z - mean, dw = v.w - mean;
  float s2 = dx * dx + dy * dy + dz * dz + dw * dw;
#pragma unroll
  for (int o = 32; o > 0; o >>= 1) s2 += __shfl_xor(s2, o);
  float rs = rsqrtf(s2 * (1.f / 256.f) + 1e-5f);
  float4 s4 = *(const float4*)(sc + lane * 4);
  float4 b4 = *(const float4*)(bi + lane * 4);
  float4 ov;
  ov.x = dx * rs * s4.x + b4.x;
  ov.y = dy * rs * s4.y + b4.y;
  ov.z = dz * rs * s4.z + b4.z;
  ov.w = dw * rs * s4.w + b4.w;
  *(float4*)(x + tok * 256 + lane * 4) = ov;
}

// ---------------- fused scoring (exact R1/R3 code) ----------------
__global__ __launch_bounds__(256) void k_score(
    const int* __restrict__ qids, const int* __restrict__ dids,
    const float* __restrict__ emb, const float* __restrict__ xq,
    const float* __restrict__ xd, const float* __restrict__ a_ptr,
    const float* __restrict__ mlp_w, float* __restrict__ out) {
  __shared__ float qmix[32 * 256];
  __shared__ float qks[32 * 11];
  __shared__ float qmask_s[32];
  int b = blockIdx.x, tid = threadIdx.x;
  float av = a_ptr[0], aw = 1.f - av;
  for (int q = 0; q < 32; ++q) {
    int qid = qids[b * 32 + q];
    float qm = qid > 0 ? 1.f : 0.f;
    float ev = emb[(size_t)qid * 256 + tid];
    float xv = xq[((size_t)b * 32 + q) * 256 + tid];
    qmix[q * 256 + tid] = (av * ev + aw * xv) * qm;
    if (tid == 0) qmask_s[q] = qm;
  }
  for (int i = tid; i < 352; i += 256) qks[i] = 0.f;
  __syncthreads();
  int j = tid;
  int did = dids[b * 256 + j];
  float dmask = did > 0 ? 1.f : 0.f;
  float sim[32];
#pragma unroll
  for (int q = 0; q < 32; ++q) sim[q] = 0.f;
  const float4* de = (const float4*)(emb + (size_t)did * 256);
  const float4* dxp = (const float4*)(xd + ((size_t)b * 256 + j) * 256);
  for (int c = 0; c < 4; ++c) {
    float4 dreg[16];
#pragma unroll
    for (int w = 0; w < 16; ++w) {
      float4 e = de[c * 16 + w], x = dxp[c * 16 + w];
      dreg[w].x = av * e.x + aw * x.x;
      dreg[w].y = av * e.y + aw * x.y;
      dreg[w].z = av * e.z + aw * x.z;
      dreg[w].w = av * e.w + aw * x.w;
    }
#pragma unroll
    for (int q = 0; q < 32; ++q) {
      const float4* qp = (const float4*)&qmix[q * 256 + c * 64];
      float d_ = 0.f;
#pragma unroll
      for (int w = 0; w < 16; ++w) {
        float4 t = qp[w];
        d_ += t.x * dreg[w].x + t.y * dreg[w].y + t.z * dreg[w].z + t.w * dreg[w].w;
      }
      sim[q] += d_;
    }
  }
  const float MU[11] = {1.f, 0.9f, 0.7f, 0.5f, 0.3f, 0.1f, -0.1f, -0.3f, -0.5f, -0.7f, -0.9f};
  const float IC[11] = {5e7f, 50.f, 50.f, 50.f, 50.f, 50.f, 50.f, 50.f, 50.f, 50.f, 50.f};
  for (int q = 0; q < 32; ++q) {
    float s = sim[q];
    float f = dmask * qmask_s[q];
#pragma unroll
    for (int k = 0; k < 11; ++k) {
      float d_ = s - MU[k];
      float v = expf(-d_ * d_ * IC[k]) * f;
#pragma unroll
      for (int o = 32; o > 0; o >>= 1) v += __shfl_xor(v, o);
      if ((tid & 63) == 0) atomicAdd(&qks[q * 11 + k], v);
    }
  }
  __syncthreads();
  if (tid < 32) {
    float qm = qmask_s[tid];
    float p = 0.f;
#pragma unroll
    for (int k = 0; k < 11; ++k) {
      float qv = qks[tid * 11 + k];
      p += mlp_w[k] * (qm * logf(fmaxf(qv, 1e-10f)) + qv * (1.f / 256.f));
    }
#pragma unroll
    for (int o = 16; o > 0; o >>= 1) p += __shfl_xor(p, o);
    if (tid == 0) out[b] = p;
  }
}

// ---------------- host-side encoder schedule ----------------
static void run_encoder(float* x, int S, int B, int CB, int FC,
    const float* Wqkv, const float* bqkv, const float* Wo, const float* bo,
    const float* l1s, const float* l1b, const float* W1, const float* b1,
    const float* W2, const float* b2, const float* l2s, const float* l2b,
    float* qkv, float* t0, float* t1, float* h, hipStream_t stream) {
  int tokens = B * S;
  int nchunk = B / CB;
  for (int l = 0; l < 2; ++l) {
    const float* wq = Wqkv + (size_t)l * 768 * 256;
    const float* bq = bqkv + l * 768;
    const float* wo = Wo + (size_t)l * 256 * 256;
    const float* bo_ = bo + l * 256;
    const float* w1 = W1 + (size_t)l * 2048 * 256;
    const float* b1_ = b1 + l * 2048;
    const float* w2 = W2 + (size_t)l * 256 * 2048;
    const float* b2_ = b2 + l * 256;
    for (int c = 0; c < nchunk; ++c) {
      float* xc = x + (size_t)c * CB * S * 256;
      int Mc = CB * S;
      k_gemm<false><<<dim3(768 / 128, Mc / 128), 256, 0, stream>>>(xc, wq, bq, qkv, Mc, 768, 256);
      if (S == 256)
        k_attn<2><<<CB * 8, 128, 0, stream>>>(qkv, t0, S, c * CB);
      else
        k_attn<1><<<CB * 8, 128, 0, stream>>>(qkv, t0, S, c * CB);
    }
    k_gemm<false><<<dim3(2, tokens / 128), 256, 0, stream>>>(t0, wo, bo_, t1, tokens, 256, 256);
    k_addln<<<tokens / 4, 256, 0, stream>>>(x, t1, l1s + l * 256, l1b + l * 256);
    for (int f = 0; f < tokens; f += FC) {
      int Mc = (tokens - f < FC) ? (tokens - f) : FC;
      k_gemm<true><<<dim3(16, Mc / 128), 256, 0, stream>>>(x + (size_t)f * 256, w1, b1_, h, Mc, 2048, 256);
      k_gemm<false><<<dim3(2, Mc / 128), 256, 0, stream>>>(h, w2, b2_, t1 + (size_t)f * 256, Mc, 256, 2048);
    }
    k_addln<<<tokens / 4, 256, 0, stream>>>(x, t1, l2s + l * 256, l2b + l * 256);
  }
}

extern "C" void kernel_launch(void* const* d_in, const int* in_sizes, int n_in,
                              void* d_out, int out_size, void* d_ws, size_t ws_size,
                              hipStream_t stream) {
  const int* qids = (const int*)d_in[0];
  const int* dids = (const int*)d_in[1];
  const float* emb = (const float*)d_in[2];
  const float* a = (const float*)d_in[3];
  const float* mlp_w = (const float*)d_in[4];
  const float* Wqkv = (const float*)d_in[5];
  const float* bqkv = (const float*)d_in[6];
  const float* Wo = (const float*)d_in[7];
  const float* bo = (const float*)d_in[8];
  const float* l1s = (const float*)d_in[9];
  const float* l1b = (const float*)d_in[10];
  const float* W1 = (const float*)d_in[11];
  const float* b1 = (const float*)d_in[12];
  const float* W2 = (const float*)d_in[13];
  const float* b2 = (const float*)d_in[14];
  const float* l2s = (const float*)d_in[15];
  const float* l2b = (const float*)d_in[16];
  float* out = (float*)d_out;
  float* ws = (float*)d_ws;

  size_t wsf = ws_size / 4;
  float* xq = ws;                    // 256*32*256
  float* xd = xq + 2097152;          // 256*256*256
  float* t0 = xd + 16777216;
  float* t1 = t0 + 16777216;
  float* qkv = t1 + 16777216;
  const size_t fixed = 2097152 + 3 * 16777216UL;

  // largest (CB, FC) that fits; (64,16384)=394MB is the known-good fallback
  const int cbs[] = {256, 128, 64, 64, 32, 16, 8, 8};
  const int fcs[] = {16384, 16384, 16384, 8192, 8192, 8192, 4096, 2048};
  int CB = 8, FC = 2048;
  for (int i = 0; i < 8; ++i) {
    if (fixed + (size_t)cbs[i] * 196608 + (size_t)fcs[i] * 2048 <= wsf) {
      CB = cbs[i]; FC = fcs[i]; break;
    }
  }
  float* h = qkv + (size_t)CB * 196608;

  k_embed<<<256 * 32 / 4, 256, 0, stream>>>(qids, emb, xq, 32);
  k_embed<<<256 * 256 / 4, 256, 0, stream>>>(dids, emb, xd, 256);

  run_encoder(xd, 256, 256, CB, FC, Wqkv, bqkv, Wo, bo, l1s, l1b, W1, b1,
              W2, b2, l2s, l2b, qkv, t0, t1, h, stream);
  int CBq = CB * 8; if (CBq > 256) CBq = 256;
  run_encoder(xq, 32, 256, CBq, FC, Wqkv, bqkv, Wo, bo, l1s, l1b, W1, b1,
              W2, b2, l2s, l2b, qkv, t0, t1, h, stream);

  k_score<<<256, 256, 0, stream>>>(qids, dids, emb, xq, xd, a, mlp_w, out);
}

// Round 5
// 9675.763 us; speedup vs baseline: 6.6853x; 2.3136x over previous
//
#include <hip/hip_runtime.h>
#include <math.h>

// KNRM-style ranker, fp32 end-to-end (kernel-0 sigma=1e-4 makes sim
// precision-critical: bf16/MFMA would flip exp-window hits).
// R5 vs R4 (22.4ms): dispatch count 55 -> 23. Unchunked (CB=256/FC=65536,
// ws>=948MB proven by R2 passing). Wo and W2 GEMMs fused with
// bias+residual+LayerNorm (64x256 tile, in-wave 16-lane LN reduce),
// removing all k_addln calls and the t1 buffer. W1/QKV keep the proven
// R4 ping-pong GEMM (67 TF). Theory under test: ~16ms of the 22.4ms is
// dispatch-count-proportional overhead/serialization, not kernel work.

#define DMODEL 256
typedef float f32x4 __attribute__((ext_vector_type(4)));

// ---------------- embed + positional encoding (4 tokens / block) ------------
__global__ __launch_bounds__(256) void k_embed(const int* __restrict__ ids,
    const float* __restrict__ emb, float* __restrict__ out_x, int S) {
  int tid = threadIdx.x;
  int tok = blockIdx.x * 4 + (tid >> 6);
  int lane = tid & 63;
  int d0 = lane * 4;
  int id = ids[tok];
  float m = id > 0 ? 1.f : 0.f;
  const float* ep = emb + (size_t)id * DMODEL + d0;
  float4 e = *(const float4*)ep;
  int s = tok % S;
  float o[4];
  float ev[4] = {e.x, e.y, e.z, e.w};
#pragma unroll
  for (int j = 0; j < 4; ++j) {
    int d = d0 + j;
    int i2 = d & ~1;
    float freq = expf((float)i2 * (-9.210340371976184f / 256.f));
    float ang = (float)s * freq;
    float pe = (d & 1) ? cosf(ang) : sinf(ang);
    o[j] = 2.f * ev[j] * m + pe;
  }
  *(float4*)(out_x + (size_t)tok * DMODEL + d0) = *(float4*)o;
}

// ---------------- fp32 GEMM (R4-proven): out[M,N] = X @ W^T + bias ----------
// 128x128x16 tile, 256 threads, 8x8 micro (4+4 split), ping-pong dbuf,
// 1 barrier per K-tile. Requires M%128==0, N%128==0, (K/16) even.
template<bool RELU>
__global__ __launch_bounds__(256) void k_gemm(const float* __restrict__ X,
    const float* __restrict__ W, const float* __restrict__ bias,
    float* __restrict__ out, int M, int N, int K) {
  __shared__ float As[2][16][128];
  __shared__ float Bs[2][16][128];
  int n0 = blockIdx.x * 128;
  int m0 = blockIdx.y * 128;
  int tid = threadIdx.x;
  int tx = tid & 15, ty = tid >> 4;
  int lr = tid >> 1;
  int lk = (tid & 1) << 3;
  const float* Xp = X + (size_t)(m0 + lr) * K + lk;
  const float* Wp = W + (size_t)(n0 + lr) * K + lk;

  float acc[8][8];
#pragma unroll
  for (int i = 0; i < 8; ++i)
#pragma unroll
    for (int j = 0; j < 8; ++j) acc[i][j] = 0.f;

  float4 a0, a1, b0, b1;

#define GLOADT(KT) do { \
    a0 = *(const float4*)(Xp + (KT)); a1 = *(const float4*)(Xp + (KT) + 4); \
    b0 = *(const float4*)(Wp + (KT)); b1 = *(const float4*)(Wp + (KT) + 4); } while (0)

#define LWRITE(BUF) do { \
    As[BUF][lk + 0][lr] = a0.x; As[BUF][lk + 1][lr] = a0.y; \
    As[BUF][lk + 2][lr] = a0.z; As[BUF][lk + 3][lr] = a0.w; \
    As[BUF][lk + 4][lr] = a1.x; As[BUF][lk + 5][lr] = a1.y; \
    As[BUF][lk + 6][lr] = a1.z; As[BUF][lk + 7][lr] = a1.w; \
    Bs[BUF][lk + 0][lr] = b0.x; Bs[BUF][lk + 1][lr] = b0.y; \
    Bs[BUF][lk + 2][lr] = b0.z; Bs[BUF][lk + 3][lr] = b0.w; \
    Bs[BUF][lk + 4][lr] = b1.x; Bs[BUF][lk + 5][lr] = b1.y; \
    Bs[BUF][lk + 6][lr] = b1.z; Bs[BUF][lk + 7][lr] = b1.w; } while (0)

#define COMPT(BUF) do { \
    _Pragma("unroll") \
    for (int k = 0; k < 16; ++k) { \
      float av[8], bv[8]; \
      *(float4*)&av[0] = *(const float4*)&As[BUF][k][ty * 4]; \
      *(float4*)&av[4] = *(const float4*)&As[BUF][k][64 + ty * 4]; \
      *(float4*)&bv[0] = *(const float4*)&Bs[BUF][k][tx * 4]; \
      *(float4*)&bv[4] = *(const float4*)&Bs[BUF][k][64 + tx * 4]; \
      _Pragma("unroll") \
      for (int i = 0; i < 8; ++i) \
        _Pragma("unroll") \
        for (int j = 0; j < 8; ++j) \
          acc[i][j] += av[i] * bv[j]; \
    } } while (0)

  const int nt = K >> 4;
  GLOADT(0);
  LWRITE(0);
  __syncthreads();
  for (int t = 0; t < nt; t += 2) {
    int k1 = (t + 1) * 16;
    GLOADT(k1);
    COMPT(0);
    LWRITE(1);
    __syncthreads();
    if (t + 2 < nt) {
      int k2 = (t + 2) * 16;
      GLOADT(k2);
      COMPT(1);
      LWRITE(0);
    } else {
      COMPT(1);
    }
    __syncthreads();
  }
#undef GLOADT
#undef LWRITE
#undef COMPT

#pragma unroll
  for (int i = 0; i < 8; ++i) {
    int mr = m0 + ((i < 4) ? (ty * 4 + i) : (64 + ty * 4 + i - 4));
#pragma unroll
    for (int jb = 0; jb < 2; ++jb) {
      int nc = n0 + jb * 64 + tx * 4;
      float4 bz = *(const float4*)(bias + nc);
      float4 o4;
      o4.x = acc[i][jb * 4 + 0] + bz.x;
      o4.y = acc[i][jb * 4 + 1] + bz.y;
      o4.z = acc[i][jb * 4 + 2] + bz.z;
      o4.w = acc[i][jb * 4 + 3] + bz.w;
      if (RELU) {
        o4.x = fmaxf(o4.x, 0.f); o4.y = fmaxf(o4.y, 0.f);
        o4.z = fmaxf(o4.z, 0.f); o4.w = fmaxf(o4.w, 0.f);
      }
      *(float4*)(out + (size_t)mr * N + nc) = o4;
    }
  }
}

// ---------------- GEMM (N=256) fused bias + residual + LayerNorm ------------
// y = LN(xres + X@W^T + bias) * lns + lnb, written in-place into xres.
// 64(M) x 256(N) tile, 256 threads: tx=tid&15 (16 col groups: cols
// q*64+tx*4+{0..3}, q=0..3), ty=tid>>4 (rows ty*4+{0..3}). LN row-reduce
// via __shfl_xor over the 16-lane row group (no barrier, no LDS).
// Requires M%64==0, K%32==0 (K=256 or 2048 here).
__global__ __launch_bounds__(256) void k_gemm_ln(const float* __restrict__ X,
    const float* __restrict__ W, const float* __restrict__ bias,
    float* __restrict__ xres, const float* __restrict__ lns,
    const float* __restrict__ lnb, int M, int K) {
  __shared__ float As[2][16][64];
  __shared__ float Bs[2][16][256];
  const int tid = threadIdx.x;
  const int m0 = blockIdx.x * 64;
  const int tx = tid & 15, ty = tid >> 4;
  const int rowA = tid & 63;            // A stage: row, wave-uniform k-quad
  const int kqA = (tid >> 6) << 2;
  const float* Xp = X + (size_t)(m0 + rowA) * K + kqA;
  const float* Wp = W + (size_t)tid * K;  // B stage: thread owns W row n=tid

  f32x4 acc[4][4];
#pragma unroll
  for (int r = 0; r < 4; ++r)
#pragma unroll
    for (int q = 0; q < 4; ++q) acc[r][q] = 0.f;

  f32x4 a, b0, b1, b2, b3;

#define GL(KT) do { \
    a  = *(const f32x4*)(Xp + (KT)); \
    b0 = *(const f32x4*)(Wp + (KT));      b1 = *(const f32x4*)(Wp + (KT) + 4); \
    b2 = *(const f32x4*)(Wp + (KT) + 8);  b3 = *(const f32x4*)(Wp + (KT) + 12); } while (0)

#define LW(BUF) do { \
    As[BUF][kqA + 0][rowA] = a[0]; As[BUF][kqA + 1][rowA] = a[1]; \
    As[BUF][kqA + 2][rowA] = a[2]; As[BUF][kqA + 3][rowA] = a[3]; \
    Bs[BUF][ 0][tid] = b0[0]; Bs[BUF][ 1][tid] = b0[1]; \
    Bs[BUF][ 2][tid] = b0[2]; Bs[BUF][ 3][tid] = b0[3]; \
    Bs[BUF][ 4][tid] = b1[0]; Bs[BUF][ 5][tid] = b1[1]; \
    Bs[BUF][ 6][tid] = b1[2]; Bs[BUF][ 7][tid] = b1[3]; \
    Bs[BUF][ 8][tid] = b2[0]; Bs[BUF][ 9][tid] = b2[1]; \
    Bs[BUF][10][tid] = b2[2]; Bs[BUF][11][tid] = b2[3]; \
    Bs[BUF][12][tid] = b3[0]; Bs[BUF][13][tid] = b3[1]; \
    Bs[BUF][14][tid] = b3[2]; Bs[BUF][15][tid] = b3[3]; } while (0)

#define CP(BUF) do { \
    _Pragma("unroll") \
    for (int k = 0; k < 16; ++k) { \
      f32x4 av = *(const f32x4*)&As[BUF][k][ty * 4]; \
      f32x4 bv0 = *(const f32x4*)&Bs[BUF][k][tx * 4]; \
      f32x4 bv1 = *(const f32x4*)&Bs[BUF][k][64 + tx * 4]; \
      f32x4 bv2 = *(const f32x4*)&Bs[BUF][k][128 + tx * 4]; \
      f32x4 bv3 = *(const f32x4*)&Bs[BUF][k][192 + tx * 4]; \
      _Pragma("unroll") \
      for (int r = 0; r < 4; ++r) { \
        acc[r][0] += av[r] * bv0; acc[r][1] += av[r] * bv1; \
        acc[r][2] += av[r] * bv2; acc[r][3] += av[r] * bv3; \
      } \
    } } while (0)

  const int nt = K >> 4;  // 16 (Wo) or 128 (W2): even
  GL(0);
  LW(0);
  __syncthreads();
  for (int t = 0; t < nt; t += 2) {
    GL((t + 1) * 16);
    CP(0);
    LW(1);
    __syncthreads();
    if (t + 2 < nt) {
      GL((t + 2) * 16);
      CP(1);
      LW(0);
    } else {
      CP(1);
    }
    __syncthreads();
  }
#undef GL
#undef LW
#undef CP

  // epilogue: v = acc + bias + xres; LN over each row (reduce across 16 lanes)
  f32x4 bza[4], sca[4], lba[4];
#pragma unroll
  for (int q = 0; q < 4; ++q) {
    int c = q * 64 + tx * 4;
    bza[q] = *(const f32x4*)(bias + c);
    sca[q] = *(const f32x4*)(lns + c);
    lba[q] = *(const f32x4*)(lnb + c);
  }
#pragma unroll
  for (int r = 0; r < 4; ++r) {
    size_t row = (size_t)m0 + ty * 4 + r;
    f32x4 v[4];
    float ps = 0.f;
#pragma unroll
    for (int q = 0; q < 4; ++q) {
      f32x4 xr = *(const f32x4*)(xres + row * 256 + q * 64 + tx * 4);
      v[q] = acc[r][q] + bza[q] + xr;
      ps += v[q][0] + v[q][1] + v[q][2] + v[q][3];
    }
    ps += __shfl_xor(ps, 1); ps += __shfl_xor(ps, 2);
    ps += __shfl_xor(ps, 4); ps += __shfl_xor(ps, 8);
    float mean = ps * (1.f / 256.f);
    float ss = 0.f;
#pragma unroll
    for (int q = 0; q < 4; ++q) {
      v[q] -= mean;
      ss += v[q][0] * v[q][0] + v[q][1] * v[q][1]
          + v[q][2] * v[q][2] + v[q][3] * v[q][3];
    }
    ss += __shfl_xor(ss, 1); ss += __shfl_xor(ss, 2);
    ss += __shfl_xor(ss, 4); ss += __shfl_xor(ss, 8);
    float rs = rsqrtf(ss * (1.f / 256.f) + 1e-5f);
#pragma unroll
    for (int q = 0; q < 4; ++q) {
      f32x4 y = v[q] * rs * sca[q] + lba[q];
      *(f32x4*)(xres + row * 256 + q * 64 + tx * 4) = y;
    }
  }
}

// ---------------- fused attention (R1/R3-proven) ----------------
template<int NR>
__global__ __launch_bounds__(128) void k_attn(const float* __restrict__ qkv,
    float* __restrict__ o, int S, int b0) {
  __shared__ float Ks[256 * 32];
  __shared__ float Vs[256 * 32];
  int bl = blockIdx.x >> 3;
  int h = blockIdx.x & 7;
  int tid = threadIdx.x;
  const float* base = qkv + (size_t)bl * S * 768;
  int hc = h * 32;
  for (int f = tid; f < S * 32; f += 128) {
    int s = f >> 5, e = f & 31;
    Ks[f] = base[(size_t)s * 768 + 256 + hc + e];
    Vs[f] = base[(size_t)s * 768 + 512 + hc + e];
  }
  __syncthreads();
  if (tid >= S) return;
  const float scale = 0.17677669529663687f;
  float q[NR][32], acc[NR][32], m[NR], l[NR];
#pragma unroll
  for (int r = 0; r < NR; ++r) {
    int row = tid + 128 * r;
    const float4* qp = (const float4*)(base + (size_t)row * 768 + hc);
#pragma unroll
    for (int w = 0; w < 8; ++w) {
      float4 t = qp[w];
      q[r][4 * w] = t.x; q[r][4 * w + 1] = t.y; q[r][4 * w + 2] = t.z; q[r][4 * w + 3] = t.w;
    }
    m[r] = -1e30f; l[r] = 0.f;
#pragma unroll
    for (int e = 0; e < 32; ++e) acc[r][e] = 0.f;
  }
  for (int j = 0; j < S; ++j) {
    float kv[32];
    const float4* kp = (const float4*)&Ks[j * 32];
#pragma unroll
    for (int w = 0; w < 8; ++w) {
      float4 t = kp[w];
      kv[4 * w] = t.x; kv[4 * w + 1] = t.y; kv[4 * w + 2] = t.z; kv[4 * w + 3] = t.w;
    }
    float p[NR];
#pragma unroll
    for (int r = 0; r < NR; ++r) {
      float dot = 0.f;
#pragma unroll
      for (int e = 0; e < 32; ++e) dot += q[r][e] * kv[e];
      float s_ = dot * scale;
      float mn = fmaxf(m[r], s_);
      p[r] = __expf(s_ - mn);
      if (mn > m[r]) {
        float al = __expf(m[r] - mn);
        l[r] *= al;
#pragma unroll
        for (int e = 0; e < 32; ++e) acc[r][e] *= al;
        m[r] = mn;
      }
      l[r] += p[r];
    }
    const float4* vp = (const float4*)&Vs[j * 32];
#pragma unroll
    for (int w = 0; w < 8; ++w) {
      float4 t = vp[w];
#pragma unroll
      for (int r = 0; r < NR; ++r) {
        acc[r][4 * w]     += p[r] * t.x;
        acc[r][4 * w + 1] += p[r] * t.y;
        acc[r][4 * w + 2] += p[r] * t.z;
        acc[r][4 * w + 3] += p[r] * t.w;
      }
    }
  }
#pragma unroll
  for (int r = 0; r < NR; ++r) {
    int row = tid + 128 * r;
    float inv = 1.f / l[r];
    float4* op = (float4*)(o + ((size_t)(b0 + bl) * S + row) * DMODEL + hc);
#pragma unroll
    for (int w = 0; w < 8; ++w) {
      float4 t;
      t.x = acc[r][4 * w] * inv;     t.y = acc[r][4 * w + 1] * inv;
      t.z = acc[r][4 * w + 2] * inv; t.w = acc[r][4 * w + 3] * inv;
      op[w] = t;
    }
  }
}

// ---------------- fused scoring (R1-proven) ----------------
__global__ __launch_bounds__(256) void k_score(
    const int* __restrict__ qids, const int* __restrict__ dids,
    const float* __restrict__ emb, const float* __restrict__ xq,
    const float* __restrict__ xd, const float* __restrict__ a_ptr,
    const float* __restrict__ mlp_w, float* __restrict__ out) {
  __shared__ float qmix[32 * 256];
  __shared__ float qks[32 * 11];
  __shared__ float qmask_s[32];
  int b = blockIdx.x, tid = threadIdx.x;
  float av = a_ptr[0], aw = 1.f - av;
  for (int q = 0; q < 32; ++q) {
    int qid = qids[b * 32 + q];
    float qm = qid > 0 ? 1.f : 0.f;
    float ev = emb[(size_t)qid * 256 + tid];
    float xv = xq[((size_t)b * 32 + q) * 256 + tid];
    qmix[q * 256 + tid] = (av * ev + aw * xv) * qm;
    if (tid == 0) qmask_s[q] = qm;
  }
  for (int i = tid; i < 352; i += 256) qks[i] = 0.f;
  __syncthreads();
  int j = tid;
  int did = dids[b * 256 + j];
  float dmask = did > 0 ? 1.f : 0.f;
  float sim[32];
#pragma unroll
  for (int q = 0; q < 32; ++q) sim[q] = 0.f;
  const float4* de = (const float4*)(emb + (size_t)did * 256);
  const float4* dxp = (const float4*)(xd + ((size_t)b * 256 + j) * 256);
  for (int c = 0; c < 4; ++c) {
    float4 dreg[16];
#pragma unroll
    for (int w = 0; w < 16; ++w) {
      float4 e = de[c * 16 + w], x = dxp[c * 16 + w];
      dreg[w].x = av * e.x + aw * x.x;
      dreg[w].y = av * e.y + aw * x.y;
      dreg[w].z = av * e.z + aw * x.z;
      dreg[w].w = av * e.w + aw * x.w;
    }
#pragma unroll
    for (int q = 0; q < 32; ++q) {
      const float4* qp = (const float4*)&qmix[q * 256 + c * 64];
      float d_ = 0.f;
#pragma unroll
      for (int w = 0; w < 16; ++w) {
        float4 t = qp[w];
        d_ += t.x * dreg[w].x + t.y * dreg[w].y + t.z * dreg[w].z + t.w * dreg[w].w;
      }
      sim[q] += d_;
    }
  }
  const float MU[11] = {1.f, 0.9f, 0.7f, 0.5f, 0.3f, 0.1f, -0.1f, -0.3f, -0.5f, -0.7f, -0.9f};
  const float IC[11] = {5e7f, 50.f, 50.f, 50.f, 50.f, 50.f, 50.f, 50.f, 50.f, 50.f, 50.f};
  for (int q = 0; q < 32; ++q) {
    float s = sim[q];
    float f = dmask * qmask_s[q];
#pragma unroll
    for (int k = 0; k < 11; ++k) {
      float d_ = s - MU[k];
      float v = expf(-d_ * d_ * IC[k]) * f;
#pragma unroll
      for (int o = 32; o > 0; o >>= 1) v += __shfl_xor(v, o);
      if ((tid & 63) == 0) atomicAdd(&qks[q * 11 + k], v);
    }
  }
  __syncthreads();
  if (tid < 32) {
    float qm = qmask_s[tid];
    float p = 0.f;
#pragma unroll
    for (int k = 0; k < 11; ++k) {
      float qv = qks[tid * 11 + k];
      p += mlp_w[k] * (qm * logf(fmaxf(qv, 1e-10f)) + qv * (1.f / 256.f));
    }
#pragma unroll
    for (int o = 16; o > 0; o >>= 1) p += __shfl_xor(p, o);
    if (tid == 0) out[b] = p;
  }
}

// ---------------- host-side encoder schedule ----------------
static void run_encoder(float* x, int S, int B, int CB, int FC,
    const float* Wqkv, const float* bqkv, const float* Wo, const float* bo,
    const float* l1s, const float* l1b, const float* W1, const float* b1,
    const float* W2, const float* b2, const float* l2s, const float* l2b,
    float* qkv, float* t0, float* h, hipStream_t stream) {
  int tokens = B * S;
  int nchunk = B / CB;
  for (int l = 0; l < 2; ++l) {
    const float* wq = Wqkv + (size_t)l * 768 * 256;
    const float* bq = bqkv + l * 768;
    const float* wo = Wo + (size_t)l * 256 * 256;
    const float* bo_ = bo + l * 256;
    const float* w1 = W1 + (size_t)l * 2048 * 256;
    const float* b1_ = b1 + l * 2048;
    const float* w2 = W2 + (size_t)l * 256 * 2048;
    const float* b2_ = b2 + l * 256;
    for (int c = 0; c < nchunk; ++c) {
      float* xc = x + (size_t)c * CB * S * 256;
      int Mc = CB * S;
      k_gemm<false><<<dim3(6, Mc / 128), 256, 0, stream>>>(xc, wq, bq, qkv, Mc, 768, 256);
      if (S == 256)
        k_attn<2><<<CB * 8, 128, 0, stream>>>(qkv, t0, S, c * CB);
      else
        k_attn<1><<<CB * 8, 128, 0, stream>>>(qkv, t0, S, c * CB);
    }
    // Wo + bias + residual + LN1, in-place into x
    k_gemm_ln<<<tokens / 64, 256, 0, stream>>>(t0, wo, bo_, x,
        l1s + l * 256, l1b + l * 256, tokens, 256);
    // FFN: W1+ReLU -> h ; W2 + bias + residual + LN2 in-place into x
    for (int f = 0; f < tokens; f += FC) {
      int Mc = (tokens - f < FC) ? (tokens - f) : FC;
      k_gemm<true><<<dim3(16, Mc / 128), 256, 0, stream>>>(x + (size_t)f * 256, w1, b1_, h, Mc, 2048, 256);
      k_gemm_ln<<<Mc / 64, 256, 0, stream>>>(h, w2, b2_, x + (size_t)f * 256,
          l2s + l * 256, l2b + l * 256, Mc, 2048);
    }
  }
}

extern "C" void kernel_launch(void* const* d_in, const int* in_sizes, int n_in,
                              void* d_out, int out_size, void* d_ws, size_t ws_size,
                              hipStream_t stream) {
  const int* qids = (const int*)d_in[0];
  const int* dids = (const int*)d_in[1];
  const float* emb = (const float*)d_in[2];
  const float* a = (const float*)d_in[3];
  const float* mlp_w = (const float*)d_in[4];
  const float* Wqkv = (const float*)d_in[5];
  const float* bqkv = (const float*)d_in[6];
  const float* Wo = (const float*)d_in[7];
  const float* bo = (const float*)d_in[8];
  const float* l1s = (const float*)d_in[9];
  const float* l1b = (const float*)d_in[10];
  const float* W1 = (const float*)d_in[11];
  const float* b1 = (const float*)d_in[12];
  const float* W2 = (const float*)d_in[13];
  const float* b2 = (const float*)d_in[14];
  const float* l2s = (const float*)d_in[15];
  const float* l2b = (const float*)d_in[16];
  float* out = (float*)d_out;
  float* ws = (float*)d_ws;

  size_t wsf = ws_size / 4;
  float* xq = ws;                    // 2,097,152
  float* xd = xq + 2097152;          // 16,777,216
  float* t0 = xd + 16777216;         // 16,777,216 (attn out)
  float* qkv = t0 + 16777216;        // CB*196608
  const size_t fixed = 2097152 + 2 * 16777216UL;

  // largest (CB, FC) that fits (R2 proved the 948MB config fits -> first wins)
  const int cbs[] = {256, 256, 128, 64, 32, 16, 8};
  const int fcs[] = {65536, 32768, 32768, 16384, 8192, 4096, 2048};
  int CB = 8, FC = 2048;
  for (int i = 0; i < 7; ++i) {
    if (fixed + (size_t)cbs[i] * 196608 + (size_t)fcs[i] * 2048 <= wsf) {
      CB = cbs[i]; FC = fcs[i]; break;
    }
  }
  float* h = qkv + (size_t)CB * 196608;

  k_embed<<<256 * 32 / 4, 256, 0, stream>>>(qids, emb, xq, 32);
  k_embed<<<256 * 256 / 4, 256, 0, stream>>>(dids, emb, xd, 256);

  run_encoder(xd, 256, 256, CB, FC, Wqkv, bqkv, Wo, bo, l1s, l1b, W1, b1,
              W2, b2, l2s, l2b, qkv, t0, h, stream);
  int CBq = CB * 8; if (CBq > 256) CBq = 256;
  run_encoder(xq, 32, 256, CBq, FC, Wqkv, bqkv, Wo, bo, l1s, l1b, W1, b1,
              W2, b2, l2s, l2b, qkv, t0, h, stream);

  k_score<<<256, 256, 0, stream>>>(qids, dids, emb, xq, xd, a, mlp_w, out);
}